// Round 3
// baseline (760.235 us; speedup 1.0000x reference)
//
#include <hip/hip_runtime.h>
#include <hip/hip_fp16.h>

#define N_NODES 100000
#define N_EDGES 1600000
#define HID 128
#define OUT_CH 64
#define N_GRAPHS 256

#define BSH 7
#define BNODES 128                                   // 1<<BSH
#define NBUCKET ((N_NODES + BNODES - 1) / BNODES)    // 782

typedef _Float16 half8 __attribute__((ext_vector_type(8)));
typedef float f32x4 __attribute__((ext_vector_type(4)));

// ---------------- init: zero bucket hist + pooled + gcnt ----------------
__global__ void k_init(int* bhist, float* pooled, float* gcnt) {
  int i = blockIdx.x * blockDim.x + threadIdx.x;
  int stride = gridDim.x * blockDim.x;
  for (int t = i; t < NBUCKET; t += stride) bhist[t] = 0;
  for (int t = i; t < N_GRAPHS * HID; t += stride) pooled[t] = 0.f;
  for (int t = i; t < N_GRAPHS; t += stride) gcnt[t] = 0.f;
}

// ---------------- bucket histogram over dst>>BSH ----------------
__global__ __launch_bounds__(256) void k_bhist(const int* __restrict__ ei,
                                               int* __restrict__ bhist) {
  __shared__ int h[NBUCKET];
  for (int i = threadIdx.x; i < NBUCKET; i += 256) h[i] = 0;
  __syncthreads();
  int stride = gridDim.x * 256;
  for (int e = blockIdx.x * 256 + threadIdx.x; e < N_EDGES; e += stride)
    atomicAdd(&h[ei[N_EDGES + e] >> BSH], 1);
  __syncthreads();
  for (int i = threadIdx.x; i < NBUCKET; i += 256)
    if (h[i]) atomicAdd(&bhist[i], h[i]);
}

// ---------------- scan buckets (1 block, 1024 threads) ----------------
__global__ __launch_bounds__(1024) void k_bscan(const int* __restrict__ bhist,
                                                int* __restrict__ boff,
                                                int* __restrict__ bcur,
                                                int* __restrict__ row_ptr) {
  __shared__ int s[1024];
  int t = threadIdx.x;
  int v = (t < NBUCKET) ? bhist[t] : 0;
  s[t] = v;
  __syncthreads();
  for (int off = 1; off < 1024; off <<= 1) {
    int a = (t >= off) ? s[t - off] : 0;
    __syncthreads();
    s[t] += a;
    __syncthreads();
  }
  if (t < NBUCKET) {
    int e = s[t] - v;     // exclusive
    boff[t] = e;
    bcur[t] = e;
  }
  if (t == 0) {
    boff[NBUCKET] = N_EDGES;
    row_ptr[N_NODES] = N_EDGES;
  }
}

// ---------------- scatter edges into bucket regions ----------------
__global__ __launch_bounds__(256) void k_bscatter(const int* __restrict__ ei,
                                                  int* __restrict__ bcur,
                                                  int2* __restrict__ bucketed) {
  int stride = gridDim.x * 256;
  for (int e = blockIdx.x * 256 + threadIdx.x; e < N_EDGES; e += stride) {
    int s = ei[e];
    int d = ei[N_EDGES + e];
    int p = atomicAdd(&bcur[d >> BSH], 1);
    bucketed[p] = make_int2(s, d);
  }
}

// ---------------- per-bucket sort: row_ptr, dinv, dst-sorted E ----------------
__global__ __launch_bounds__(256) void k_bsort(const int2* __restrict__ bucketed,
                                               const int* __restrict__ boff,
                                               int* __restrict__ row_ptr,
                                               float* __restrict__ dinv,
                                               int2* __restrict__ E) {
  __shared__ int cnt[BNODES];
  __shared__ int cur[BNODES];
  int b = blockIdx.x, t = threadIdx.x;
  int node0 = b << BSH;
  int e0 = boff[b], e1 = boff[b + 1];
  if (t < BNODES) cnt[t] = 0;
  __syncthreads();
  for (int p = e0 + t; p < e1; p += 256)
    atomicAdd(&cnt[bucketed[p].y - node0], 1);
  __syncthreads();
  if (t < BNODES) cur[t] = cnt[t];
  __syncthreads();
  for (int off = 1; off < BNODES; off <<= 1) {
    int a = (t < BNODES && t >= off) ? cur[t - off] : 0;
    __syncthreads();
    if (t < BNODES) cur[t] += a;
    __syncthreads();
  }
  if (t < BNODES) {
    int excl = cur[t] - cnt[t];
    int node = node0 + t;
    if (node < N_NODES) {
      row_ptr[node] = e0 + excl;
      dinv[node] = rsqrtf((float)cnt[t] + 1.0f);   // +1 self-loop
    }
    cur[t] = e0 + excl;
  }
  __syncthreads();
  for (int p = e0 + t; p < e1; p += 256) {
    int2 e = bucketed[p];
    int q = atomicAdd(&cur[e.y - node0], 1);
    E[q] = e;                                      // {src, dst}; norm later
  }
}

// ---------------- compute edge norms (all dinv ready) ----------------
__global__ __launch_bounds__(256) void k_norm(int2* __restrict__ E,
                                              const float* __restrict__ dinv) {
  int p = blockIdx.x * 256 + threadIdx.x;
  if (p < N_EDGES) {
    int2 e = E[p];
    E[p] = make_int2(e.x, __float_as_int(dinv[e.x] * dinv[e.y]));
  }
}

// ---------------- transpose weights to fp16 [n][k] ----------------
__global__ __launch_bounds__(256) void k_wtrans(const float* __restrict__ w1,
                                                const float* __restrict__ w2,
                                                const float* __restrict__ w3,
                                                __half* __restrict__ wt1,
                                                __half* __restrict__ wt2,
                                                __half* __restrict__ wt3) {
  int idx = blockIdx.x * 256 + threadIdx.x;        // n*128 + k
  int n = idx >> 7, k = idx & 127;
  const float* w = (blockIdx.y == 0) ? w1 : (blockIdx.y == 1) ? w2 : w3;
  __half* wt = (blockIdx.y == 0) ? wt1 : (blockIdx.y == 1) ? wt2 : wt3;
  wt[idx] = __float2half(w[k * HID + n]);
}

// ---------------- MFMA fp16 GEMM: T[M,128] = H[M,128] @ W ----------------
#define GBM 64
__global__ __launch_bounds__(256) void k_gemm(const float* __restrict__ H,
                                              const __half* __restrict__ WT,  // [n][k]
                                              __half* __restrict__ T) {
  __shared__ __half hs[GBM * HID];    // swizzled [r][k]
  __shared__ __half ws[HID * HID];    // swizzled [n][k]
  int tid = threadIdx.x;
  int m0 = blockIdx.x * GBM;

  // stage H (fp32 -> fp16), 8-half granules, XOR-swizzled
  for (int g = tid; g < GBM * 16; g += 256) {
    int r = g >> 4, kg = g & 15;
    int row = m0 + r;
    float4 f0 = {0, 0, 0, 0}, f1 = {0, 0, 0, 0};
    if (row < N_NODES) {
      f0 = *(const float4*)&H[(size_t)row * HID + kg * 8];
      f1 = *(const float4*)&H[(size_t)row * HID + kg * 8 + 4];
    }
    half8 h;
    h[0] = (_Float16)f0.x; h[1] = (_Float16)f0.y; h[2] = (_Float16)f0.z; h[3] = (_Float16)f0.w;
    h[4] = (_Float16)f1.x; h[5] = (_Float16)f1.y; h[6] = (_Float16)f1.z; h[7] = (_Float16)f1.w;
    int byte = (r * HID + kg * 8) * 2;
    byte ^= (r & 7) << 4;
    *(half8*)((char*)hs + byte) = h;
  }
  // stage WT, XOR-swizzled
  for (int g = tid; g < HID * 16; g += 256) {
    int n = g >> 4, kg = g & 15;
    half8 h = *(const half8*)&WT[n * HID + kg * 8];
    int byte = (n * HID + kg * 8) * 2;
    byte ^= (n & 7) << 4;
    *(half8*)((char*)ws + byte) = h;
  }
  __syncthreads();

  int w = tid >> 6, l = tid & 63;
  int r = (w << 4) + (l & 15);        // row strip: wave w -> rows w*16..w*16+15
  int kq = (l >> 4) << 3;             // k-octet base 0/8/16/24
  f32x4 acc[8] = {};

  #pragma unroll
  for (int kc = 0; kc < HID; kc += 32) {
    int abyte = ((r * HID + kc + kq) * 2) ^ ((r & 7) << 4);
    half8 a = *(const half8*)((char*)hs + abyte);
    #pragma unroll
    for (int nb = 0; nb < 8; ++nb) {
      int n = nb * 16 + (l & 15);
      int bbyte = ((n * HID + kc + kq) * 2) ^ ((n & 7) << 4);
      half8 bfr = *(const half8*)((char*)ws + bbyte);
      acc[nb] = __builtin_amdgcn_mfma_f32_16x16x32_f16(a, bfr, acc[nb], 0, 0, 0);
    }
  }

  // C/D: col = l&15, row = (l>>4)*4 + j
  int orow0 = m0 + (w << 4) + ((l >> 4) << 2);
  int ocol = l & 15;
  #pragma unroll
  for (int nb = 0; nb < 8; ++nb) {
    #pragma unroll
    for (int j = 0; j < 4; ++j) {
      int row = orow0 + j;
      if (row < N_NODES)
        T[(size_t)row * HID + nb * 16 + ocol] = __float2half(acc[nb][j]);
    }
  }
}

// ---------------- aggregation: wave/node, lane=2ch, unroll-8 gathers ----------------
__global__ __launch_bounds__(256) void k_agg(const __half* __restrict__ T,
                                             const int* __restrict__ row_ptr,
                                             const int2* __restrict__ E,
                                             const float* __restrict__ dinv,
                                             const float* __restrict__ bias,
                                             float* __restrict__ Hout) {
  int wid = (blockIdx.x * blockDim.x + threadIdx.x) >> 6;  // node id
  int lane = threadIdx.x & 63;
  if (wid >= N_NODES) return;
  const __half2* T2 = (const __half2*)T;
  float dn = dinv[wid];
  float2 t = __half22float2(T2[(size_t)wid * 64 + lane]);
  float ax = dn * dn * t.x;                    // self-loop term
  float ay = dn * dn * t.y;
  int p = row_ptr[wid], p1 = row_ptr[wid + 1];
  for (; p + 8 <= p1; p += 8) {
    int2 e0 = E[p],     e1 = E[p + 1], e2 = E[p + 2], e3 = E[p + 3];
    int2 e4 = E[p + 4], e5 = E[p + 5], e6 = E[p + 6], e7 = E[p + 7];
    __half2 v0 = T2[(size_t)e0.x * 64 + lane];
    __half2 v1 = T2[(size_t)e1.x * 64 + lane];
    __half2 v2 = T2[(size_t)e2.x * 64 + lane];
    __half2 v3 = T2[(size_t)e3.x * 64 + lane];
    __half2 v4 = T2[(size_t)e4.x * 64 + lane];
    __half2 v5 = T2[(size_t)e5.x * 64 + lane];
    __half2 v6 = T2[(size_t)e6.x * 64 + lane];
    __half2 v7 = T2[(size_t)e7.x * 64 + lane];
    float2 f0 = __half22float2(v0), f1 = __half22float2(v1);
    float2 f2 = __half22float2(v2), f3 = __half22float2(v3);
    float2 f4 = __half22float2(v4), f5 = __half22float2(v5);
    float2 f6 = __half22float2(v6), f7 = __half22float2(v7);
    float w0 = __int_as_float(e0.y), w1 = __int_as_float(e1.y);
    float w2 = __int_as_float(e2.y), w3 = __int_as_float(e3.y);
    float w4 = __int_as_float(e4.y), w5 = __int_as_float(e5.y);
    float w6 = __int_as_float(e6.y), w7 = __int_as_float(e7.y);
    ax += w0 * f0.x; ay += w0 * f0.y;
    ax += w1 * f1.x; ay += w1 * f1.y;
    ax += w2 * f2.x; ay += w2 * f2.y;
    ax += w3 * f3.x; ay += w3 * f3.y;
    ax += w4 * f4.x; ay += w4 * f4.y;
    ax += w5 * f5.x; ay += w5 * f5.y;
    ax += w6 * f6.x; ay += w6 * f6.y;
    ax += w7 * f7.x; ay += w7 * f7.y;
  }
  for (; p < p1; ++p) {
    int2 e = E[p];
    float2 f = __half22float2(T2[(size_t)e.x * 64 + lane]);
    float w = __int_as_float(e.y);
    ax += w * f.x; ay += w * f.y;
  }
  float2 b = ((const float2*)bias)[lane];
  float2 o;
  o.x = fmaxf(ax + b.x, 0.f);
  o.y = fmaxf(ay + b.y, 0.f);
  ((float2*)Hout)[(size_t)wid * 64 + lane] = o;
}

// ---------------- mean pool (batch is sorted -> run-length flush) ----------------
#define NODES_PER_BLOCK 64
__global__ __launch_bounds__(128) void k_pool(const float* __restrict__ H,
                                              const int* __restrict__ batch,
                                              float* __restrict__ pooled,
                                              float* __restrict__ gcnt) {
  int c = threadIdx.x;                       // channel 0..127
  int n0 = blockIdx.x * NODES_PER_BLOCK;
  if (n0 >= N_NODES) return;
  int n1 = min(n0 + NODES_PER_BLOCK, N_NODES);
  float sum = 0.f;
  float cntr = 0.f;
  int cur = batch[n0];
  for (int n = n0; n < n1; ++n) {
    int g = batch[n];
    if (g != cur) {
      atomicAdd(&pooled[cur * HID + c], sum);
      if (c == 0) atomicAdd(&gcnt[cur], cntr);
      sum = 0.f; cntr = 0.f; cur = g;
    }
    sum += H[(size_t)n * HID + c];
    cntr += 1.f;
  }
  atomicAdd(&pooled[cur * HID + c], sum);
  if (c == 0) atomicAdd(&gcnt[cur], cntr);
}

// ---------------- output GEMM ----------------
__global__ __launch_bounds__(64) void k_out(const float* __restrict__ pooled,
                                            const float* __restrict__ gcnt,
                                            const float* __restrict__ w_out,
                                            const float* __restrict__ b_out,
                                            float* __restrict__ out) {
  int g = blockIdx.x;    // 0..255
  int c = threadIdx.x;   // 0..63
  __shared__ float p[HID];
  float inv = 1.0f / fmaxf(gcnt[g], 1.0f);
  for (int k = c; k < HID; k += 64) p[k] = pooled[g * HID + k] * inv;
  __syncthreads();
  float acc = b_out[c];
  #pragma unroll 8
  for (int k = 0; k < HID; ++k) acc += p[k] * w_out[k * OUT_CH + c];
  out[g * OUT_CH + c] = acc;
}

extern "C" void kernel_launch(void* const* d_in, const int* in_sizes, int n_in,
                              void* d_out, int out_size, void* d_ws, size_t ws_size,
                              hipStream_t stream) {
  const float* x     = (const float*)d_in[0];
  const int*   ei    = (const int*)d_in[1];
  const int*   batch = (const int*)d_in[2];
  const float* w1    = (const float*)d_in[3];
  const float* b1    = (const float*)d_in[4];
  const float* w2    = (const float*)d_in[5];
  const float* b2    = (const float*)d_in[6];
  const float* w3    = (const float*)d_in[7];
  const float* b3    = (const float*)d_in[8];
  const float* w_out = (const float*)d_in[9];
  const float* b_out = (const float*)d_in[10];
  float* out = (float*)d_out;

  // workspace carve-up
  char* w = (char*)d_ws;
  auto alloc = [&](size_t bytes) { void* p = (void*)w; w += (bytes + 255) & ~(size_t)255; return p; };
  int*   bhist    = (int*)  alloc((size_t)NBUCKET * 4);
  int*   boff     = (int*)  alloc((size_t)(NBUCKET + 1) * 4);
  int*   bcur     = (int*)  alloc((size_t)NBUCKET * 4);
  int*   row_ptr  = (int*)  alloc((size_t)(N_NODES + 1) * 4);
  float* dinv     = (float*)alloc((size_t)N_NODES * 4);
  int2*  bucketed = (int2*) alloc((size_t)N_EDGES * 8);
  int2*  E        = (int2*) alloc((size_t)N_EDGES * 8);
  __half* wt1     = (__half*)alloc((size_t)HID * HID * 2);
  __half* wt2     = (__half*)alloc((size_t)HID * HID * 2);
  __half* wt3     = (__half*)alloc((size_t)HID * HID * 2);
  __half* T       = (__half*)alloc((size_t)N_NODES * HID * 2);
  float* H0       = (float*)alloc((size_t)N_NODES * HID * 4);
  float* pooled   = (float*)alloc((size_t)N_GRAPHS * HID * 4);
  float* gcnt     = (float*)alloc((size_t)N_GRAPHS * 4);

  const int EB = (N_EDGES + 255) / 256;        // 6250
  const int GB = (N_NODES + GBM - 1) / GBM;    // 1563
  const int AB = (N_NODES + 3) / 4;            // 25000
  const int PB = (N_NODES + NODES_PER_BLOCK - 1) / NODES_PER_BLOCK;

  k_init<<<64, 256, 0, stream>>>(bhist, pooled, gcnt);
  k_bhist<<<256, 256, 0, stream>>>(ei, bhist);
  k_bscan<<<1, 1024, 0, stream>>>(bhist, boff, bcur, row_ptr);
  k_bscatter<<<2048, 256, 0, stream>>>(ei, bcur, bucketed);
  k_bsort<<<NBUCKET, 256, 0, stream>>>(bucketed, boff, row_ptr, dinv, E);
  k_norm<<<EB, 256, 0, stream>>>(E, dinv);
  dim3 wtg(64, 3);
  k_wtrans<<<wtg, 256, 0, stream>>>(w1, w2, w3, wt1, wt2, wt3);

  // layer 1
  k_gemm<<<GB, 256, 0, stream>>>(x, wt1, T);
  k_agg<<<AB, 256, 0, stream>>>(T, row_ptr, E, dinv, b1, H0);
  // layer 2
  k_gemm<<<GB, 256, 0, stream>>>(H0, wt2, T);
  k_agg<<<AB, 256, 0, stream>>>(T, row_ptr, E, dinv, b2, H0);
  // layer 3
  k_gemm<<<GB, 256, 0, stream>>>(H0, wt3, T);
  k_agg<<<AB, 256, 0, stream>>>(T, row_ptr, E, dinv, b3, H0);

  k_pool<<<PB, 128, 0, stream>>>(H0, batch, pooled, gcnt);
  k_out<<<N_GRAPHS, 64, 0, stream>>>(pooled, gcnt, w_out, b_out, out);
}

// Round 4
// 489.886 us; speedup vs baseline: 1.5519x; 1.5519x over previous
//
#include <hip/hip_runtime.h>
#include <hip/hip_fp16.h>

#define N_NODES 100000
#define N_EDGES 1600000
#define HID 128
#define OUT_CH 64
#define N_GRAPHS 256
#define CHUNK 1024
#define NCHUNK ((N_NODES + CHUNK - 1) / CHUNK)   // 98

typedef _Float16 half8 __attribute__((ext_vector_type(8)));
typedef float f32x4 __attribute__((ext_vector_type(4)));

// ---------------- init ----------------
__global__ void k_init(int* cnt, float* pooled, float* gcnt) {
  int i = blockIdx.x * blockDim.x + threadIdx.x;
  int stride = gridDim.x * blockDim.x;
  for (int t = i; t < N_NODES; t += stride) cnt[t] = 0;
  for (int t = i; t < N_GRAPHS * HID; t += stride) pooled[t] = 0.f;
  for (int t = i; t < N_GRAPHS; t += stride) gcnt[t] = 0.f;
}

// ---------------- degree count (in-edges per dst) ----------------
__global__ void k_edge_count(const int* __restrict__ ei, int* __restrict__ cnt) {
  int e = blockIdx.x * blockDim.x + threadIdx.x;
  if (e < N_EDGES) atomicAdd(&cnt[ei[N_EDGES + e]], 1);
}

// ---------------- hierarchical exclusive scan ----------------
__global__ void k_scan1(const int* __restrict__ cnt, int* __restrict__ row_ptr,
                        int* __restrict__ chunk_sums) {
  __shared__ int s[CHUNK];
  int t = threadIdx.x;
  int gid = blockIdx.x * CHUNK + t;
  int v = (gid < N_NODES) ? cnt[gid] : 0;
  s[t] = v;
  __syncthreads();
  for (int off = 1; off < CHUNK; off <<= 1) {
    int add = (t >= off) ? s[t - off] : 0;
    __syncthreads();
    s[t] += add;
    __syncthreads();
  }
  if (gid < N_NODES) row_ptr[gid] = s[t] - v;     // chunk-local exclusive
  if (t == CHUNK - 1) chunk_sums[blockIdx.x] = s[t];
}

__global__ void k_scan2(const int* __restrict__ chunk_sums, int* __restrict__ chunk_off) {
  __shared__ int s[128];
  int t = threadIdx.x;
  int v = (t < NCHUNK) ? chunk_sums[t] : 0;
  s[t] = v;
  __syncthreads();
  for (int off = 1; off < 128; off <<= 1) {
    int add = (t >= off) ? s[t - off] : 0;
    __syncthreads();
    s[t] += add;
    __syncthreads();
  }
  if (t < NCHUNK) chunk_off[t] = s[t] - v;        // exclusive
}

__global__ void k_scan3(int* __restrict__ row_ptr, const int* __restrict__ chunk_off,
                        int* __restrict__ cursor) {
  int i = blockIdx.x * blockDim.x + threadIdx.x;
  if (i < N_NODES) {
    int v = row_ptr[i] + chunk_off[i / CHUNK];
    row_ptr[i] = v;
    cursor[i] = v;
  }
  if (i == 0) row_ptr[N_NODES] = N_EDGES;
}

__global__ void k_dinv(const int* __restrict__ cnt, float* __restrict__ dinv) {
  int i = blockIdx.x * blockDim.x + threadIdx.x;
  if (i < N_NODES) dinv[i] = rsqrtf((float)cnt[i] + 1.0f);  // +1 self-loop
}

// ---------------- CSR fill: E[p] = {src, bits(norm)} sorted by dst ----------------
__global__ void k_csr_fill(const int* __restrict__ ei, const float* __restrict__ dinv,
                           int* __restrict__ cursor, int2* __restrict__ E) {
  int e = blockIdx.x * blockDim.x + threadIdx.x;
  if (e < N_EDGES) {
    int s = ei[e];
    int d = ei[N_EDGES + e];
    int p = atomicAdd(&cursor[d], 1);
    E[p] = make_int2(s, __float_as_int(dinv[s] * dinv[d]));
  }
}

// ---------------- transpose weights to fp16 [n][k] ----------------
__global__ __launch_bounds__(256) void k_wtrans(const float* __restrict__ w1,
                                                const float* __restrict__ w2,
                                                const float* __restrict__ w3,
                                                __half* __restrict__ wt1,
                                                __half* __restrict__ wt2,
                                                __half* __restrict__ wt3) {
  int idx = blockIdx.x * 256 + threadIdx.x;        // n*128 + k
  int n = idx >> 7, k = idx & 127;
  const float* w = (blockIdx.y == 0) ? w1 : (blockIdx.y == 1) ? w2 : w3;
  __half* wt = (blockIdx.y == 0) ? wt1 : (blockIdx.y == 1) ? wt2 : wt3;
  wt[idx] = __float2half(w[k * HID + n]);
}

// ---------------- MFMA fp16 GEMM: T[M,128] = H[M,128] @ W ----------------
#define GBM 64
template <bool FP16IN>
__global__ __launch_bounds__(256) void k_gemm(const void* __restrict__ Hv,
                                              const __half* __restrict__ WT,  // [n][k]
                                              __half* __restrict__ T) {
  __shared__ __half hs[GBM * HID];    // swizzled [r][k]
  __shared__ __half ws[HID * HID];    // swizzled [n][k]
  int tid = threadIdx.x;
  int m0 = blockIdx.x * GBM;

  // stage H -> fp16, 8-half granules, XOR-swizzled
  for (int g = tid; g < GBM * 16; g += 256) {
    int r = g >> 4, kg = g & 15;
    int row = m0 + r;
    half8 h = {};
    if (row < N_NODES) {
      if constexpr (FP16IN) {
        h = *(const half8*)&((const _Float16*)Hv)[(size_t)row * HID + kg * 8];
      } else {
        const float* H = (const float*)Hv;
        float4 f0 = *(const float4*)&H[(size_t)row * HID + kg * 8];
        float4 f1 = *(const float4*)&H[(size_t)row * HID + kg * 8 + 4];
        h[0] = (_Float16)f0.x; h[1] = (_Float16)f0.y; h[2] = (_Float16)f0.z; h[3] = (_Float16)f0.w;
        h[4] = (_Float16)f1.x; h[5] = (_Float16)f1.y; h[6] = (_Float16)f1.z; h[7] = (_Float16)f1.w;
      }
    }
    int byte = (r * HID + kg * 8) * 2;
    byte ^= (r & 7) << 4;
    *(half8*)((char*)hs + byte) = h;
  }
  // stage WT, XOR-swizzled
  for (int g = tid; g < HID * 16; g += 256) {
    int n = g >> 4, kg = g & 15;
    half8 h = *(const half8*)&WT[n * HID + kg * 8];
    int byte = (n * HID + kg * 8) * 2;
    byte ^= (n & 7) << 4;
    *(half8*)((char*)ws + byte) = h;
  }
  __syncthreads();

  int w = tid >> 6, l = tid & 63;
  int r = (w << 4) + (l & 15);        // wave w -> rows w*16..w*16+15
  int kq = (l >> 4) << 3;             // k-octet base 0/8/16/24
  f32x4 acc[8] = {};

  #pragma unroll
  for (int kc = 0; kc < HID; kc += 32) {
    int abyte = ((r * HID + kc + kq) * 2) ^ ((r & 7) << 4);
    half8 a = *(const half8*)((char*)hs + abyte);
    #pragma unroll
    for (int nb = 0; nb < 8; ++nb) {
      int n = nb * 16 + (l & 15);
      int bbyte = ((n * HID + kc + kq) * 2) ^ ((n & 7) << 4);
      half8 bfr = *(const half8*)((char*)ws + bbyte);
      acc[nb] = __builtin_amdgcn_mfma_f32_16x16x32_f16(a, bfr, acc[nb], 0, 0, 0);
    }
  }

  // C/D: col = l&15, row = (l>>4)*4 + j
  int orow0 = m0 + (w << 4) + ((l >> 4) << 2);
  int ocol = l & 15;
  #pragma unroll
  for (int nb = 0; nb < 8; ++nb) {
    #pragma unroll
    for (int j = 0; j < 4; ++j) {
      int row = orow0 + j;
      if (row < N_NODES)
        T[(size_t)row * HID + nb * 16 + ocol] = __float2half(acc[nb][j]);
    }
  }
}

// ---------------- aggregation: wave/node, lane=2ch, unroll-8 gathers ----------------
__global__ __launch_bounds__(256) void k_agg(const __half* __restrict__ T,
                                             const int* __restrict__ row_ptr,
                                             const int2* __restrict__ E,
                                             const float* __restrict__ dinv,
                                             const float* __restrict__ bias,
                                             __half* __restrict__ Hout) {
  int wid = (blockIdx.x * blockDim.x + threadIdx.x) >> 6;  // node id
  int lane = threadIdx.x & 63;
  if (wid >= N_NODES) return;
  const __half2* T2 = (const __half2*)T;
  float dn = dinv[wid];
  float2 t = __half22float2(T2[(size_t)wid * 64 + lane]);
  float ax = dn * dn * t.x;                    // self-loop term
  float ay = dn * dn * t.y;
  int p = row_ptr[wid], p1 = row_ptr[wid + 1];
  for (; p + 8 <= p1; p += 8) {
    int2 e0 = E[p],     e1 = E[p + 1], e2 = E[p + 2], e3 = E[p + 3];
    int2 e4 = E[p + 4], e5 = E[p + 5], e6 = E[p + 6], e7 = E[p + 7];
    __half2 v0 = T2[(size_t)e0.x * 64 + lane];
    __half2 v1 = T2[(size_t)e1.x * 64 + lane];
    __half2 v2 = T2[(size_t)e2.x * 64 + lane];
    __half2 v3 = T2[(size_t)e3.x * 64 + lane];
    __half2 v4 = T2[(size_t)e4.x * 64 + lane];
    __half2 v5 = T2[(size_t)e5.x * 64 + lane];
    __half2 v6 = T2[(size_t)e6.x * 64 + lane];
    __half2 v7 = T2[(size_t)e7.x * 64 + lane];
    float2 f0 = __half22float2(v0), f1 = __half22float2(v1);
    float2 f2 = __half22float2(v2), f3 = __half22float2(v3);
    float2 f4 = __half22float2(v4), f5 = __half22float2(v5);
    float2 f6 = __half22float2(v6), f7 = __half22float2(v7);
    float w0 = __int_as_float(e0.y), w1 = __int_as_float(e1.y);
    float w2 = __int_as_float(e2.y), w3 = __int_as_float(e3.y);
    float w4 = __int_as_float(e4.y), w5 = __int_as_float(e5.y);
    float w6 = __int_as_float(e6.y), w7 = __int_as_float(e7.y);
    ax += w0 * f0.x; ay += w0 * f0.y;
    ax += w1 * f1.x; ay += w1 * f1.y;
    ax += w2 * f2.x; ay += w2 * f2.y;
    ax += w3 * f3.x; ay += w3 * f3.y;
    ax += w4 * f4.x; ay += w4 * f4.y;
    ax += w5 * f5.x; ay += w5 * f5.y;
    ax += w6 * f6.x; ay += w6 * f6.y;
    ax += w7 * f7.x; ay += w7 * f7.y;
  }
  for (; p < p1; ++p) {
    int2 e = E[p];
    float2 f = __half22float2(T2[(size_t)e.x * 64 + lane]);
    float w = __int_as_float(e.y);
    ax += w * f.x; ay += w * f.y;
  }
  float2 b = ((const float2*)bias)[lane];
  __half2 o = __floats2half2_rn(fmaxf(ax + b.x, 0.f), fmaxf(ay + b.y, 0.f));
  ((__half2*)Hout)[(size_t)wid * 64 + lane] = o;
}

// ---------------- mean pool (batch is sorted -> run-length flush) ----------------
#define NODES_PER_BLOCK 64
__global__ __launch_bounds__(128) void k_pool(const __half* __restrict__ H,
                                              const int* __restrict__ batch,
                                              float* __restrict__ pooled,
                                              float* __restrict__ gcnt) {
  int c = threadIdx.x;                       // channel 0..127
  int n0 = blockIdx.x * NODES_PER_BLOCK;
  if (n0 >= N_NODES) return;
  int n1 = min(n0 + NODES_PER_BLOCK, N_NODES);
  float sum = 0.f;
  float cntr = 0.f;
  int cur = batch[n0];
  for (int n = n0; n < n1; ++n) {
    int g = batch[n];
    if (g != cur) {
      atomicAdd(&pooled[cur * HID + c], sum);
      if (c == 0) atomicAdd(&gcnt[cur], cntr);
      sum = 0.f; cntr = 0.f; cur = g;
    }
    sum += __half2float(H[(size_t)n * HID + c]);
    cntr += 1.f;
  }
  atomicAdd(&pooled[cur * HID + c], sum);
  if (c == 0) atomicAdd(&gcnt[cur], cntr);
}

// ---------------- output GEMM ----------------
__global__ __launch_bounds__(64) void k_out(const float* __restrict__ pooled,
                                            const float* __restrict__ gcnt,
                                            const float* __restrict__ w_out,
                                            const float* __restrict__ b_out,
                                            float* __restrict__ out) {
  int g = blockIdx.x;    // 0..255
  int c = threadIdx.x;   // 0..63
  __shared__ float p[HID];
  float inv = 1.0f / fmaxf(gcnt[g], 1.0f);
  for (int k = c; k < HID; k += 64) p[k] = pooled[g * HID + k] * inv;
  __syncthreads();
  float acc = b_out[c];
  #pragma unroll 8
  for (int k = 0; k < HID; ++k) acc += p[k] * w_out[k * OUT_CH + c];
  out[g * OUT_CH + c] = acc;
}

extern "C" void kernel_launch(void* const* d_in, const int* in_sizes, int n_in,
                              void* d_out, int out_size, void* d_ws, size_t ws_size,
                              hipStream_t stream) {
  const float* x     = (const float*)d_in[0];
  const int*   ei    = (const int*)d_in[1];
  const int*   batch = (const int*)d_in[2];
  const float* w1    = (const float*)d_in[3];
  const float* b1    = (const float*)d_in[4];
  const float* w2    = (const float*)d_in[5];
  const float* b2    = (const float*)d_in[6];
  const float* w3    = (const float*)d_in[7];
  const float* b3    = (const float*)d_in[8];
  const float* w_out = (const float*)d_in[9];
  const float* b_out = (const float*)d_in[10];
  float* out = (float*)d_out;

  // workspace carve-up
  char* w = (char*)d_ws;
  auto alloc = [&](size_t bytes) { void* p = (void*)w; w += (bytes + 255) & ~(size_t)255; return p; };
  int*   cnt        = (int*)  alloc((size_t)N_NODES * 4);
  int*   row_ptr    = (int*)  alloc((size_t)(N_NODES + 1) * 4);
  int*   cursor     = (int*)  alloc((size_t)N_NODES * 4);
  float* dinv       = (float*)alloc((size_t)N_NODES * 4);
  int*   chunk_sums = (int*)  alloc((size_t)NCHUNK * 4);
  int*   chunk_off  = (int*)  alloc((size_t)NCHUNK * 4);
  int2*  E          = (int2*) alloc((size_t)N_EDGES * 8);
  __half* wt1       = (__half*)alloc((size_t)HID * HID * 2);
  __half* wt2       = (__half*)alloc((size_t)HID * HID * 2);
  __half* wt3       = (__half*)alloc((size_t)HID * HID * 2);
  __half* T         = (__half*)alloc((size_t)N_NODES * HID * 2);
  __half* Hh        = (__half*)alloc((size_t)N_NODES * HID * 2);
  float* pooled     = (float*)alloc((size_t)N_GRAPHS * HID * 4);
  float* gcnt       = (float*)alloc((size_t)N_GRAPHS * 4);

  const int EB = (N_EDGES + 255) / 256;        // 6250
  const int NB = (N_NODES + 255) / 256;        // 391
  const int GB = (N_NODES + GBM - 1) / GBM;    // 1563
  const int AB = (N_NODES + 3) / 4;            // 25000
  const int PB = (N_NODES + NODES_PER_BLOCK - 1) / NODES_PER_BLOCK;

  k_init<<<256, 256, 0, stream>>>(cnt, pooled, gcnt);
  k_edge_count<<<EB, 256, 0, stream>>>(ei, cnt);
  k_scan1<<<NCHUNK, CHUNK, 0, stream>>>(cnt, row_ptr, chunk_sums);
  k_scan2<<<1, 128, 0, stream>>>(chunk_sums, chunk_off);
  k_scan3<<<NB, 256, 0, stream>>>(row_ptr, chunk_off, cursor);
  k_dinv<<<NB, 256, 0, stream>>>(cnt, dinv);
  k_csr_fill<<<EB, 256, 0, stream>>>(ei, dinv, cursor, E);
  dim3 wtg(64, 3);
  k_wtrans<<<wtg, 256, 0, stream>>>(w1, w2, w3, wt1, wt2, wt3);

  // layer 1
  k_gemm<false><<<GB, 256, 0, stream>>>(x, wt1, T);
  k_agg<<<AB, 256, 0, stream>>>(T, row_ptr, E, dinv, b1, Hh);
  // layer 2
  k_gemm<true><<<GB, 256, 0, stream>>>(Hh, wt2, T);
  k_agg<<<AB, 256, 0, stream>>>(T, row_ptr, E, dinv, b2, Hh);
  // layer 3
  k_gemm<true><<<GB, 256, 0, stream>>>(Hh, wt3, T);
  k_agg<<<AB, 256, 0, stream>>>(T, row_ptr, E, dinv, b3, Hh);

  k_pool<<<PB, 128, 0, stream>>>(Hh, batch, pooled, gcnt);
  k_out<<<N_GRAPHS, 64, 0, stream>>>(pooled, gcnt, w_out, b_out, out);
}

// Round 5
// 476.064 us; speedup vs baseline: 1.5969x; 1.0290x over previous
//
#include <hip/hip_runtime.h>
#include <hip/hip_fp16.h>

#define N_NODES 100000
#define N_EDGES 1600000
#define HID 128
#define OUT_CH 64
#define N_GRAPHS 256
#define CHUNK 1024
#define NCHUNK ((N_NODES + CHUNK - 1) / CHUNK)   // 98
#define NSLICE 8
#define SLICE_NODES ((N_NODES + NSLICE - 1) / NSLICE)  // 12500

typedef _Float16 half8 __attribute__((ext_vector_type(8)));
typedef float f32x4 __attribute__((ext_vector_type(4)));

// ---------------- init ----------------
__global__ void k_init(int* cnt, float* pooled, float* gcnt) {
  int i = blockIdx.x * blockDim.x + threadIdx.x;
  int stride = gridDim.x * blockDim.x;
  for (int t = i; t < N_NODES; t += stride) cnt[t] = 0;
  for (int t = i; t < N_GRAPHS * HID; t += stride) pooled[t] = 0.f;
  for (int t = i; t < N_GRAPHS; t += stride) gcnt[t] = 0.f;
}

// ---------------- degree count, XCD-sliced by dst range ----------------
__global__ __launch_bounds__(256) void k_edge_count(const int* __restrict__ ei,
                                                    int* __restrict__ cnt) {
  int slice = blockIdx.x & (NSLICE - 1);
  int lo = slice * SLICE_NODES;
  int hi = min(lo + SLICE_NODES, N_NODES);
  int bi = blockIdx.x >> 3;
  int step = (gridDim.x >> 3) * 256;
  for (int e = bi * 256 + threadIdx.x; e < N_EDGES; e += step) {
    int d = ei[N_EDGES + e];
    if (d >= lo && d < hi) atomicAdd(&cnt[d], 1);
  }
}

// ---------------- hierarchical exclusive scan ----------------
__global__ void k_scan1(const int* __restrict__ cnt, int* __restrict__ row_ptr,
                        int* __restrict__ chunk_sums) {
  __shared__ int s[CHUNK];
  int t = threadIdx.x;
  int gid = blockIdx.x * CHUNK + t;
  int v = (gid < N_NODES) ? cnt[gid] : 0;
  s[t] = v;
  __syncthreads();
  for (int off = 1; off < CHUNK; off <<= 1) {
    int add = (t >= off) ? s[t - off] : 0;
    __syncthreads();
    s[t] += add;
    __syncthreads();
  }
  if (gid < N_NODES) row_ptr[gid] = s[t] - v;     // chunk-local exclusive
  if (t == CHUNK - 1) chunk_sums[blockIdx.x] = s[t];
}

__global__ void k_scan2(const int* __restrict__ chunk_sums, int* __restrict__ chunk_off) {
  __shared__ int s[128];
  int t = threadIdx.x;
  int v = (t < NCHUNK) ? chunk_sums[t] : 0;
  s[t] = v;
  __syncthreads();
  for (int off = 1; off < 128; off <<= 1) {
    int add = (t >= off) ? s[t - off] : 0;
    __syncthreads();
    s[t] += add;
    __syncthreads();
  }
  if (t < NCHUNK) chunk_off[t] = s[t] - v;        // exclusive
}

// scan finalize + cursor init + dinv (merged)
__global__ void k_scan3(int* __restrict__ row_ptr, const int* __restrict__ chunk_off,
                        int* __restrict__ cursor, const int* __restrict__ cnt,
                        float* __restrict__ dinv) {
  int i = blockIdx.x * blockDim.x + threadIdx.x;
  if (i < N_NODES) {
    int v = row_ptr[i] + chunk_off[i / CHUNK];
    row_ptr[i] = v;
    cursor[i] = v;
    dinv[i] = rsqrtf((float)cnt[i] + 1.0f);        // +1 self-loop
  }
  if (i == 0) row_ptr[N_NODES] = N_EDGES;
}

// ---------------- CSR fill, XCD-sliced: E[p]={src,bits(norm)} ----------------
__global__ __launch_bounds__(256) void k_csr_fill(const int* __restrict__ ei,
                                                  const float* __restrict__ dinv,
                                                  int* __restrict__ cursor,
                                                  int2* __restrict__ E) {
  int slice = blockIdx.x & (NSLICE - 1);
  int lo = slice * SLICE_NODES;
  int hi = min(lo + SLICE_NODES, N_NODES);
  int bi = blockIdx.x >> 3;
  int step = (gridDim.x >> 3) * 256;
  for (int e = bi * 256 + threadIdx.x; e < N_EDGES; e += step) {
    int d = ei[N_EDGES + e];
    if (d >= lo && d < hi) {
      int s = ei[e];
      int p = atomicAdd(&cursor[d], 1);
      E[p] = make_int2(s, __float_as_int(dinv[s] * dinv[d]));
    }
  }
}

// ---------------- transpose weights to fp16 [n][k] ----------------
__global__ __launch_bounds__(256) void k_wtrans(const float* __restrict__ w1,
                                                const float* __restrict__ w2,
                                                const float* __restrict__ w3,
                                                __half* __restrict__ wt1,
                                                __half* __restrict__ wt2,
                                                __half* __restrict__ wt3) {
  int idx = blockIdx.x * 256 + threadIdx.x;        // n*128 + k
  int n = idx >> 7, k = idx & 127;
  const float* w = (blockIdx.y == 0) ? w1 : (blockIdx.y == 1) ? w2 : w3;
  __half* wt = (blockIdx.y == 0) ? wt1 : (blockIdx.y == 1) ? wt2 : wt3;
  wt[idx] = __float2half(w[k * HID + n]);
}

// ---------------- MFMA fp16 GEMM: T[M,128] = H[M,128] @ W ----------------
#define GBM 64
template <bool FP16IN>
__global__ __launch_bounds__(256) void k_gemm(const void* __restrict__ Hv,
                                              const __half* __restrict__ WT,  // [n][k]
                                              __half* __restrict__ T) {
  __shared__ __half hs[GBM * HID];    // swizzled [r][k]
  __shared__ __half ws[HID * HID];    // swizzled [n][k]
  int tid = threadIdx.x;
  int m0 = blockIdx.x * GBM;

  // stage H -> fp16, 8-half granules, XOR-swizzled
  for (int g = tid; g < GBM * 16; g += 256) {
    int r = g >> 4, kg = g & 15;
    int row = m0 + r;
    half8 h = {};
    if (row < N_NODES) {
      if constexpr (FP16IN) {
        h = *(const half8*)&((const _Float16*)Hv)[(size_t)row * HID + kg * 8];
      } else {
        const float* H = (const float*)Hv;
        float4 f0 = *(const float4*)&H[(size_t)row * HID + kg * 8];
        float4 f1 = *(const float4*)&H[(size_t)row * HID + kg * 8 + 4];
        h[0] = (_Float16)f0.x; h[1] = (_Float16)f0.y; h[2] = (_Float16)f0.z; h[3] = (_Float16)f0.w;
        h[4] = (_Float16)f1.x; h[5] = (_Float16)f1.y; h[6] = (_Float16)f1.z; h[7] = (_Float16)f1.w;
      }
    }
    int byte = (r * HID + kg * 8) * 2;
    byte ^= (r & 7) << 4;
    *(half8*)((char*)hs + byte) = h;
  }
  // stage WT, XOR-swizzled
  for (int g = tid; g < HID * 16; g += 256) {
    int n = g >> 4, kg = g & 15;
    half8 h = *(const half8*)&WT[n * HID + kg * 8];
    int byte = (n * HID + kg * 8) * 2;
    byte ^= (n & 7) << 4;
    *(half8*)((char*)ws + byte) = h;
  }
  __syncthreads();

  int w = tid >> 6, l = tid & 63;
  int r = (w << 4) + (l & 15);        // wave w -> rows w*16..w*16+15
  int kq = (l >> 4) << 3;             // k-octet base 0/8/16/24
  f32x4 acc[8] = {};

  #pragma unroll
  for (int kc = 0; kc < HID; kc += 32) {
    int abyte = ((r * HID + kc + kq) * 2) ^ ((r & 7) << 4);
    half8 a = *(const half8*)((char*)hs + abyte);
    #pragma unroll
    for (int nb = 0; nb < 8; ++nb) {
      int n = nb * 16 + (l & 15);
      int bbyte = ((n * HID + kc + kq) * 2) ^ ((n & 7) << 4);
      half8 bfr = *(const half8*)((char*)ws + bbyte);
      acc[nb] = __builtin_amdgcn_mfma_f32_16x16x32_f16(a, bfr, acc[nb], 0, 0, 0);
    }
  }

  // C/D: col = l&15, row = (l>>4)*4 + j
  int orow0 = m0 + (w << 4) + ((l >> 4) << 2);
  int ocol = l & 15;
  #pragma unroll
  for (int nb = 0; nb < 8; ++nb) {
    #pragma unroll
    for (int j = 0; j < 4; ++j) {
      int row = orow0 + j;
      if (row < N_NODES)
        T[(size_t)row * HID + nb * 16 + ocol] = __float2half(acc[nb][j]);
    }
  }
}

// ---------------- aggregation: wave/node, lane=2ch, unroll-8 gathers ----------------
__global__ __launch_bounds__(256) void k_agg(const __half* __restrict__ T,
                                             const int* __restrict__ row_ptr,
                                             const int2* __restrict__ E,
                                             const float* __restrict__ dinv,
                                             const float* __restrict__ bias,
                                             __half* __restrict__ Hout) {
  int wid = (blockIdx.x * blockDim.x + threadIdx.x) >> 6;  // node id
  int lane = threadIdx.x & 63;
  if (wid >= N_NODES) return;
  const __half2* T2 = (const __half2*)T;
  float dn = dinv[wid];
  float2 t = __half22float2(T2[(size_t)wid * 64 + lane]);
  float ax = dn * dn * t.x;                    // self-loop term
  float ay = dn * dn * t.y;
  int p = row_ptr[wid], p1 = row_ptr[wid + 1];
  for (; p + 8 <= p1; p += 8) {
    int2 e0 = E[p],     e1 = E[p + 1], e2 = E[p + 2], e3 = E[p + 3];
    int2 e4 = E[p + 4], e5 = E[p + 5], e6 = E[p + 6], e7 = E[p + 7];
    __half2 v0 = T2[(size_t)e0.x * 64 + lane];
    __half2 v1 = T2[(size_t)e1.x * 64 + lane];
    __half2 v2 = T2[(size_t)e2.x * 64 + lane];
    __half2 v3 = T2[(size_t)e3.x * 64 + lane];
    __half2 v4 = T2[(size_t)e4.x * 64 + lane];
    __half2 v5 = T2[(size_t)e5.x * 64 + lane];
    __half2 v6 = T2[(size_t)e6.x * 64 + lane];
    __half2 v7 = T2[(size_t)e7.x * 64 + lane];
    float2 f0 = __half22float2(v0), f1 = __half22float2(v1);
    float2 f2 = __half22float2(v2), f3 = __half22float2(v3);
    float2 f4 = __half22float2(v4), f5 = __half22float2(v5);
    float2 f6 = __half22float2(v6), f7 = __half22float2(v7);
    float w0 = __int_as_float(e0.y), w1 = __int_as_float(e1.y);
    float w2 = __int_as_float(e2.y), w3 = __int_as_float(e3.y);
    float w4 = __int_as_float(e4.y), w5 = __int_as_float(e5.y);
    float w6 = __int_as_float(e6.y), w7 = __int_as_float(e7.y);
    ax += w0 * f0.x; ay += w0 * f0.y;
    ax += w1 * f1.x; ay += w1 * f1.y;
    ax += w2 * f2.x; ay += w2 * f2.y;
    ax += w3 * f3.x; ay += w3 * f3.y;
    ax += w4 * f4.x; ay += w4 * f4.y;
    ax += w5 * f5.x; ay += w5 * f5.y;
    ax += w6 * f6.x; ay += w6 * f6.y;
    ax += w7 * f7.x; ay += w7 * f7.y;
  }
  for (; p < p1; ++p) {
    int2 e = E[p];
    float2 f = __half22float2(T2[(size_t)e.x * 64 + lane]);
    float w = __int_as_float(e.y);
    ax += w * f.x; ay += w * f.y;
  }
  float2 b = ((const float2*)bias)[lane];
  __half2 o = __floats2half2_rn(fmaxf(ax + b.x, 0.f), fmaxf(ay + b.y, 0.f));
  ((__half2*)Hout)[(size_t)wid * 64 + lane] = o;
}

// ---------------- mean pool (batch is sorted -> run-length flush) ----------------
#define NODES_PER_BLOCK 64
__global__ __launch_bounds__(128) void k_pool(const __half* __restrict__ H,
                                              const int* __restrict__ batch,
                                              float* __restrict__ pooled,
                                              float* __restrict__ gcnt) {
  int c = threadIdx.x;                       // channel 0..127
  int n0 = blockIdx.x * NODES_PER_BLOCK;
  if (n0 >= N_NODES) return;
  int n1 = min(n0 + NODES_PER_BLOCK, N_NODES);
  float sum = 0.f;
  float cntr = 0.f;
  int cur = batch[n0];
  for (int n = n0; n < n1; ++n) {
    int g = batch[n];
    if (g != cur) {
      atomicAdd(&pooled[cur * HID + c], sum);
      if (c == 0) atomicAdd(&gcnt[cur], cntr);
      sum = 0.f; cntr = 0.f; cur = g;
    }
    sum += __half2float(H[(size_t)n * HID + c]);
    cntr += 1.f;
  }
  atomicAdd(&pooled[cur * HID + c], sum);
  if (c == 0) atomicAdd(&gcnt[cur], cntr);
}

// ---------------- output GEMM ----------------
__global__ __launch_bounds__(64) void k_out(const float* __restrict__ pooled,
                                            const float* __restrict__ gcnt,
                                            const float* __restrict__ w_out,
                                            const float* __restrict__ b_out,
                                            float* __restrict__ out) {
  int g = blockIdx.x;    // 0..255
  int c = threadIdx.x;   // 0..63
  __shared__ float p[HID];
  float inv = 1.0f / fmaxf(gcnt[g], 1.0f);
  for (int k = c; k < HID; k += 64) p[k] = pooled[g * HID + k] * inv;
  __syncthreads();
  float acc = b_out[c];
  #pragma unroll 8
  for (int k = 0; k < HID; ++k) acc += p[k] * w_out[k * OUT_CH + c];
  out[g * OUT_CH + c] = acc;
}

extern "C" void kernel_launch(void* const* d_in, const int* in_sizes, int n_in,
                              void* d_out, int out_size, void* d_ws, size_t ws_size,
                              hipStream_t stream) {
  const float* x     = (const float*)d_in[0];
  const int*   ei    = (const int*)d_in[1];
  const int*   batch = (const int*)d_in[2];
  const float* w1    = (const float*)d_in[3];
  const float* b1    = (const float*)d_in[4];
  const float* w2    = (const float*)d_in[5];
  const float* b2    = (const float*)d_in[6];
  const float* w3    = (const float*)d_in[7];
  const float* b3    = (const float*)d_in[8];
  const float* w_out = (const float*)d_in[9];
  const float* b_out = (const float*)d_in[10];
  float* out = (float*)d_out;

  // workspace carve-up
  char* w = (char*)d_ws;
  auto alloc = [&](size_t bytes) { void* p = (void*)w; w += (bytes + 255) & ~(size_t)255; return p; };
  int*   cnt        = (int*)  alloc((size_t)N_NODES * 4);
  int*   row_ptr    = (int*)  alloc((size_t)(N_NODES + 1) * 4);
  int*   cursor     = (int*)  alloc((size_t)N_NODES * 4);
  float* dinv       = (float*)alloc((size_t)N_NODES * 4);
  int*   chunk_sums = (int*)  alloc((size_t)NCHUNK * 4);
  int*   chunk_off  = (int*)  alloc((size_t)NCHUNK * 4);
  int2*  E          = (int2*) alloc((size_t)N_EDGES * 8);
  __half* wt1       = (__half*)alloc((size_t)HID * HID * 2);
  __half* wt2       = (__half*)alloc((size_t)HID * HID * 2);
  __half* wt3       = (__half*)alloc((size_t)HID * HID * 2);
  __half* T         = (__half*)alloc((size_t)N_NODES * HID * 2);
  __half* Hh        = (__half*)alloc((size_t)N_NODES * HID * 2);
  float* pooled     = (float*)alloc((size_t)N_GRAPHS * HID * 4);
  float* gcnt       = (float*)alloc((size_t)N_GRAPHS * 4);

  const int NB = (N_NODES + 255) / 256;        // 391
  const int GB = (N_NODES + GBM - 1) / GBM;    // 1563
  const int AB = (N_NODES + 3) / 4;            // 25000
  const int PB = (N_NODES + NODES_PER_BLOCK - 1) / NODES_PER_BLOCK;

  k_init<<<256, 256, 0, stream>>>(cnt, pooled, gcnt);
  k_edge_count<<<2048, 256, 0, stream>>>(ei, cnt);
  k_scan1<<<NCHUNK, CHUNK, 0, stream>>>(cnt, row_ptr, chunk_sums);
  k_scan2<<<1, 128, 0, stream>>>(chunk_sums, chunk_off);
  k_scan3<<<NB, 256, 0, stream>>>(row_ptr, chunk_off, cursor, cnt, dinv);
  k_csr_fill<<<2048, 256, 0, stream>>>(ei, dinv, cursor, E);
  dim3 wtg(64, 3);
  k_wtrans<<<wtg, 256, 0, stream>>>(w1, w2, w3, wt1, wt2, wt3);

  // layer 1
  k_gemm<false><<<GB, 256, 0, stream>>>(x, wt1, T);
  k_agg<<<AB, 256, 0, stream>>>(T, row_ptr, E, dinv, b1, Hh);
  // layer 2
  k_gemm<true><<<GB, 256, 0, stream>>>(Hh, wt2, T);
  k_agg<<<AB, 256, 0, stream>>>(T, row_ptr, E, dinv, b2, Hh);
  // layer 3
  k_gemm<true><<<GB, 256, 0, stream>>>(Hh, wt3, T);
  k_agg<<<AB, 256, 0, stream>>>(T, row_ptr, E, dinv, b3, Hh);

  k_pool<<<PB, 128, 0, stream>>>(Hh, batch, pooled, gcnt);
  k_out<<<N_GRAPHS, 64, 0, stream>>>(pooled, gcnt, w_out, b_out, out);
}

// Round 6
// 433.900 us; speedup vs baseline: 1.7521x; 1.0972x over previous
//
#include <hip/hip_runtime.h>
#include <hip/hip_fp16.h>

#define N_NODES 100000
#define N_EDGES 1600000
#define HID 128
#define OUT_CH 64
#define N_GRAPHS 256
#define CHUNK 1024
#define NCHUNK ((N_NODES + CHUNK - 1) / CHUNK)   // 98
#define NSLICE 8
#define SLICE_NODES ((N_NODES + NSLICE - 1) / NSLICE)  // 12500

typedef _Float16 half8 __attribute__((ext_vector_type(8)));
typedef float f32x4 __attribute__((ext_vector_type(4)));

// ---------------- init ----------------
__global__ void k_init(int* cnt, float* pooled, float* gcnt) {
  int i = blockIdx.x * blockDim.x + threadIdx.x;
  int stride = gridDim.x * blockDim.x;
  for (int t = i; t < N_NODES; t += stride) cnt[t] = 0;
  for (int t = i; t < N_GRAPHS * HID; t += stride) pooled[t] = 0.f;
  for (int t = i; t < N_GRAPHS; t += stride) gcnt[t] = 0.f;
}

// ---------------- degree count, XCD-sliced by dst range ----------------
__global__ __launch_bounds__(256) void k_edge_count(const int* __restrict__ ei,
                                                    int* __restrict__ cnt) {
  int slice = blockIdx.x & (NSLICE - 1);
  int lo = slice * SLICE_NODES;
  int hi = min(lo + SLICE_NODES, N_NODES);
  int bi = blockIdx.x >> 3;
  int step = (gridDim.x >> 3) * 256;
  for (int e = bi * 256 + threadIdx.x; e < N_EDGES; e += step) {
    int d = ei[N_EDGES + e];
    if (d >= lo && d < hi) atomicAdd(&cnt[d], 1);
  }
}

// ---------------- hierarchical exclusive scan ----------------
__global__ void k_scan1(const int* __restrict__ cnt, int* __restrict__ row_ptr,
                        int* __restrict__ chunk_sums) {
  __shared__ int s[CHUNK];
  int t = threadIdx.x;
  int gid = blockIdx.x * CHUNK + t;
  int v = (gid < N_NODES) ? cnt[gid] : 0;
  s[t] = v;
  __syncthreads();
  for (int off = 1; off < CHUNK; off <<= 1) {
    int add = (t >= off) ? s[t - off] : 0;
    __syncthreads();
    s[t] += add;
    __syncthreads();
  }
  if (gid < N_NODES) row_ptr[gid] = s[t] - v;     // chunk-local exclusive
  if (t == CHUNK - 1) chunk_sums[blockIdx.x] = s[t];
}

__global__ void k_scan2(const int* __restrict__ chunk_sums, int* __restrict__ chunk_off) {
  __shared__ int s[128];
  int t = threadIdx.x;
  int v = (t < NCHUNK) ? chunk_sums[t] : 0;
  s[t] = v;
  __syncthreads();
  for (int off = 1; off < 128; off <<= 1) {
    int add = (t >= off) ? s[t - off] : 0;
    __syncthreads();
    s[t] += add;
    __syncthreads();
  }
  if (t < NCHUNK) chunk_off[t] = s[t] - v;        // exclusive
}

// scan finalize + cursor init + dinv (merged)
__global__ void k_scan3(int* __restrict__ row_ptr, const int* __restrict__ chunk_off,
                        int* __restrict__ cursor, const int* __restrict__ cnt,
                        float* __restrict__ dinv) {
  int i = blockIdx.x * blockDim.x + threadIdx.x;
  if (i < N_NODES) {
    int v = row_ptr[i] + chunk_off[i / CHUNK];
    row_ptr[i] = v;
    cursor[i] = v;
    dinv[i] = rsqrtf((float)cnt[i] + 1.0f);        // +1 self-loop
  }
  if (i == 0) row_ptr[N_NODES] = N_EDGES;
}

// ---------------- CSR fill, XCD-sliced: E[p]={src,bits(norm)} ----------------
__global__ __launch_bounds__(256) void k_csr_fill(const int* __restrict__ ei,
                                                  const float* __restrict__ dinv,
                                                  int* __restrict__ cursor,
                                                  int2* __restrict__ E) {
  int slice = blockIdx.x & (NSLICE - 1);
  int lo = slice * SLICE_NODES;
  int hi = min(lo + SLICE_NODES, N_NODES);
  int bi = blockIdx.x >> 3;
  int step = (gridDim.x >> 3) * 256;
  for (int e = bi * 256 + threadIdx.x; e < N_EDGES; e += step) {
    int d = ei[N_EDGES + e];
    if (d >= lo && d < hi) {
      int s = ei[e];
      int p = atomicAdd(&cursor[d], 1);
      E[p] = make_int2(s, __float_as_int(dinv[s] * dinv[d]));
    }
  }
}

// ---------------- transpose weights to fp16 [n][k] ----------------
__global__ __launch_bounds__(256) void k_wtrans(const float* __restrict__ w1,
                                                const float* __restrict__ w2,
                                                const float* __restrict__ w3,
                                                __half* __restrict__ wt1,
                                                __half* __restrict__ wt2,
                                                __half* __restrict__ wt3) {
  int idx = blockIdx.x * 256 + threadIdx.x;        // n*128 + k
  int n = idx >> 7, k = idx & 127;
  const float* w = (blockIdx.y == 0) ? w1 : (blockIdx.y == 1) ? w2 : w3;
  __half* wt = (blockIdx.y == 0) ? wt1 : (blockIdx.y == 1) ? wt2 : wt3;
  wt[idx] = __float2half(w[k * HID + n]);
}

// ---------------- MFMA fp16 GEMM: T[M,128] = H[M,128] @ W ----------------
#define GBM 64
template <bool FP16IN>
__global__ __launch_bounds__(256) void k_gemm(const void* __restrict__ Hv,
                                              const __half* __restrict__ WT,  // [n][k]
                                              __half* __restrict__ T) {
  __shared__ __half hs[GBM * HID];    // swizzled [r][k]; reused for epilogue
  __shared__ __half ws[HID * HID];    // swizzled [n][k]
  int tid = threadIdx.x;
  int m0 = blockIdx.x * GBM;

  // stage H -> fp16, 8-half granules, XOR-swizzled
  for (int g = tid; g < GBM * 16; g += 256) {
    int r = g >> 4, kg = g & 15;
    int row = m0 + r;
    half8 h = {};
    if (row < N_NODES) {
      if constexpr (FP16IN) {
        h = *(const half8*)&((const _Float16*)Hv)[(size_t)row * HID + kg * 8];
      } else {
        const float* H = (const float*)Hv;
        float4 f0 = *(const float4*)&H[(size_t)row * HID + kg * 8];
        float4 f1 = *(const float4*)&H[(size_t)row * HID + kg * 8 + 4];
        h[0] = (_Float16)f0.x; h[1] = (_Float16)f0.y; h[2] = (_Float16)f0.z; h[3] = (_Float16)f0.w;
        h[4] = (_Float16)f1.x; h[5] = (_Float16)f1.y; h[6] = (_Float16)f1.z; h[7] = (_Float16)f1.w;
      }
    }
    int byte = (r * HID + kg * 8) * 2;
    byte ^= (r & 7) << 4;
    *(half8*)((char*)hs + byte) = h;
  }
  // stage WT, XOR-swizzled
  for (int g = tid; g < HID * 16; g += 256) {
    int n = g >> 4, kg = g & 15;
    half8 h = *(const half8*)&WT[n * HID + kg * 8];
    int byte = (n * HID + kg * 8) * 2;
    byte ^= (n & 7) << 4;
    *(half8*)((char*)ws + byte) = h;
  }
  __syncthreads();

  int w = tid >> 6, l = tid & 63;
  int r = (w << 4) + (l & 15);        // wave w -> rows w*16..w*16+15
  int kq = (l >> 4) << 3;             // k-octet base 0/8/16/24
  f32x4 acc[8] = {};

  #pragma unroll
  for (int kc = 0; kc < HID; kc += 32) {
    int abyte = ((r * HID + kc + kq) * 2) ^ ((r & 7) << 4);
    half8 a = *(const half8*)((char*)hs + abyte);
    #pragma unroll
    for (int nb = 0; nb < 8; ++nb) {
      int n = nb * 16 + (l & 15);
      int bbyte = ((n * HID + kc + kq) * 2) ^ ((n & 7) << 4);
      half8 bfr = *(const half8*)((char*)ws + bbyte);
      acc[nb] = __builtin_amdgcn_mfma_f32_16x16x32_f16(a, bfr, acc[nb], 0, 0, 0);
    }
  }

  // ---- epilogue: acc -> LDS (swizzled) -> coalesced 16B stores ----
  __syncthreads();   // everyone done reading hs
  // C/D: col = l&15, row = (l>>4)*4 + j (within wave strip)
  #pragma unroll
  for (int nb = 0; nb < 8; ++nb) {
    #pragma unroll
    for (int j = 0; j < 4; ++j) {
      int rr = (w << 4) + ((l >> 4) << 2) + j;
      int cc = nb * 16 + (l & 15);
      int byte = (rr * HID + cc) * 2;
      byte ^= (rr & 7) << 4;
      *(__half*)((char*)hs + byte) = __float2half(acc[nb][j]);
    }
  }
  __syncthreads();
  for (int g = tid; g < GBM * 16; g += 256) {
    int rr = g >> 4, kg = g & 15;
    int byte = (rr * HID + kg * 8) * 2;
    byte ^= (rr & 7) << 4;
    half8 v = *(half8*)((char*)hs + byte);
    int row = m0 + rr;
    if (row < N_NODES)
      *(half8*)&((_Float16*)T)[(size_t)row * HID + kg * 8] = v;
  }
}

// ---------------- aggregation: wave/node, quad-per-edge, 16B/lane gathers ----------------
__device__ __forceinline__ void acc8(float* acc, uint4 v, float wt) {
  __half2 h0 = *(__half2*)&v.x, h1 = *(__half2*)&v.y;
  __half2 h2 = *(__half2*)&v.z, h3 = *(__half2*)&v.w;
  float2 f0 = __half22float2(h0), f1 = __half22float2(h1);
  float2 f2 = __half22float2(h2), f3 = __half22float2(h3);
  acc[0] += wt * f0.x; acc[1] += wt * f0.y;
  acc[2] += wt * f1.x; acc[3] += wt * f1.y;
  acc[4] += wt * f2.x; acc[5] += wt * f2.y;
  acc[6] += wt * f3.x; acc[7] += wt * f3.y;
}

__global__ __launch_bounds__(256) void k_agg(const __half* __restrict__ T,
                                             const int* __restrict__ row_ptr,
                                             const int2* __restrict__ E,
                                             const float* __restrict__ dinv,
                                             const float* __restrict__ bias,
                                             __half* __restrict__ Hout) {
  int wid = (blockIdx.x * blockDim.x + threadIdx.x) >> 6;  // node id
  int lane = threadIdx.x & 63;
  if (wid >= N_NODES) return;
  int q = lane >> 4;          // quad 0..3: edge slot
  int wch = lane & 15;        // channel group: ch 8*wch .. 8*wch+7

  float acc[8] = {};
  float dn = dinv[wid];
  // self-loop: weight dn*dn in quad 0 only (others 0)
  {
    uint4 vs = *(const uint4*)(T + (size_t)wid * HID + wch * 8);
    acc8(acc, vs, (q == 0) ? dn * dn : 0.f);
  }
  int p0 = row_ptr[wid], p1 = row_ptr[wid + 1];
  for (int p = p0; p < p1; p += 8) {
    int iA = p + q, iB = p + 4 + q;
    int cA = min(iA, p1 - 1), cB = min(iB, p1 - 1);
    int2 eA = E[cA];
    int2 eB = E[cB];
    uint4 vA = *(const uint4*)(T + (size_t)eA.x * HID + wch * 8);
    uint4 vB = *(const uint4*)(T + (size_t)eB.x * HID + wch * 8);
    float wA = (iA < p1) ? __int_as_float(eA.y) : 0.f;
    float wB = (iB < p1) ? __int_as_float(eB.y) : 0.f;
    acc8(acc, vA, wA);
    acc8(acc, vB, wB);
  }
  // cross-quad reduction (lanes {wch, wch+16, wch+32, wch+48})
  #pragma unroll
  for (int j = 0; j < 8; ++j) {
    acc[j] += __shfl_xor(acc[j], 16, 64);
    acc[j] += __shfl_xor(acc[j], 32, 64);
  }
  if (q == 0) {
    float4 b0 = *(const float4*)(bias + wch * 8);
    float4 b1 = *(const float4*)(bias + wch * 8 + 4);
    __half2 o0 = __floats2half2_rn(fmaxf(acc[0] + b0.x, 0.f), fmaxf(acc[1] + b0.y, 0.f));
    __half2 o1 = __floats2half2_rn(fmaxf(acc[2] + b0.z, 0.f), fmaxf(acc[3] + b0.w, 0.f));
    __half2 o2 = __floats2half2_rn(fmaxf(acc[4] + b1.x, 0.f), fmaxf(acc[5] + b1.y, 0.f));
    __half2 o3 = __floats2half2_rn(fmaxf(acc[6] + b1.z, 0.f), fmaxf(acc[7] + b1.w, 0.f));
    uint4 o;
    o.x = *(unsigned int*)&o0; o.y = *(unsigned int*)&o1;
    o.z = *(unsigned int*)&o2; o.w = *(unsigned int*)&o3;
    *(uint4*)(Hout + (size_t)wid * HID + wch * 8) = o;
  }
}

// ---------------- mean pool (batch is sorted -> run-length flush) ----------------
#define NODES_PER_BLOCK 64
__global__ __launch_bounds__(128) void k_pool(const __half* __restrict__ H,
                                              const int* __restrict__ batch,
                                              float* __restrict__ pooled,
                                              float* __restrict__ gcnt) {
  int c = threadIdx.x;                       // channel 0..127
  int n0 = blockIdx.x * NODES_PER_BLOCK;
  if (n0 >= N_NODES) return;
  int n1 = min(n0 + NODES_PER_BLOCK, N_NODES);
  float sum = 0.f;
  float cntr = 0.f;
  int cur = batch[n0];
  for (int n = n0; n < n1; ++n) {
    int g = batch[n];
    if (g != cur) {
      atomicAdd(&pooled[cur * HID + c], sum);
      if (c == 0) atomicAdd(&gcnt[cur], cntr);
      sum = 0.f; cntr = 0.f; cur = g;
    }
    sum += __half2float(H[(size_t)n * HID + c]);
    cntr += 1.f;
  }
  atomicAdd(&pooled[cur * HID + c], sum);
  if (c == 0) atomicAdd(&gcnt[cur], cntr);
}

// ---------------- output GEMM ----------------
__global__ __launch_bounds__(64) void k_out(const float* __restrict__ pooled,
                                            const float* __restrict__ gcnt,
                                            const float* __restrict__ w_out,
                                            const float* __restrict__ b_out,
                                            float* __restrict__ out) {
  int g = blockIdx.x;    // 0..255
  int c = threadIdx.x;   // 0..63
  __shared__ float p[HID];
  float inv = 1.0f / fmaxf(gcnt[g], 1.0f);
  for (int k = c; k < HID; k += 64) p[k] = pooled[g * HID + k] * inv;
  __syncthreads();
  float acc = b_out[c];
  #pragma unroll 8
  for (int k = 0; k < HID; ++k) acc += p[k] * w_out[k * OUT_CH + c];
  out[g * OUT_CH + c] = acc;
}

extern "C" void kernel_launch(void* const* d_in, const int* in_sizes, int n_in,
                              void* d_out, int out_size, void* d_ws, size_t ws_size,
                              hipStream_t stream) {
  const float* x     = (const float*)d_in[0];
  const int*   ei    = (const int*)d_in[1];
  const int*   batch = (const int*)d_in[2];
  const float* w1    = (const float*)d_in[3];
  const float* b1    = (const float*)d_in[4];
  const float* w2    = (const float*)d_in[5];
  const float* b2    = (const float*)d_in[6];
  const float* w3    = (const float*)d_in[7];
  const float* b3    = (const float*)d_in[8];
  const float* w_out = (const float*)d_in[9];
  const float* b_out = (const float*)d_in[10];
  float* out = (float*)d_out;

  // workspace carve-up
  char* w = (char*)d_ws;
  auto alloc = [&](size_t bytes) { void* p = (void*)w; w += (bytes + 255) & ~(size_t)255; return p; };
  int*   cnt        = (int*)  alloc((size_t)N_NODES * 4);
  int*   row_ptr    = (int*)  alloc((size_t)(N_NODES + 1) * 4);
  int*   cursor     = (int*)  alloc((size_t)N_NODES * 4);
  float* dinv       = (float*)alloc((size_t)N_NODES * 4);
  int*   chunk_sums = (int*)  alloc((size_t)NCHUNK * 4);
  int*   chunk_off  = (int*)  alloc((size_t)NCHUNK * 4);
  int2*  E          = (int2*) alloc((size_t)N_EDGES * 8);
  __half* wt1       = (__half*)alloc((size_t)HID * HID * 2);
  __half* wt2       = (__half*)alloc((size_t)HID * HID * 2);
  __half* wt3       = (__half*)alloc((size_t)HID * HID * 2);
  __half* T         = (__half*)alloc((size_t)N_NODES * HID * 2);
  __half* Hh        = (__half*)alloc((size_t)N_NODES * HID * 2);
  float* pooled     = (float*)alloc((size_t)N_GRAPHS * HID * 4);
  float* gcnt       = (float*)alloc((size_t)N_GRAPHS * 4);

  const int NB = (N_NODES + 255) / 256;        // 391
  const int GB = (N_NODES + GBM - 1) / GBM;    // 1563
  const int AB = (N_NODES + 3) / 4;            // 25000
  const int PB = (N_NODES + NODES_PER_BLOCK - 1) / NODES_PER_BLOCK;

  k_init<<<256, 256, 0, stream>>>(cnt, pooled, gcnt);
  k_edge_count<<<2048, 256, 0, stream>>>(ei, cnt);
  k_scan1<<<NCHUNK, CHUNK, 0, stream>>>(cnt, row_ptr, chunk_sums);
  k_scan2<<<1, 128, 0, stream>>>(chunk_sums, chunk_off);
  k_scan3<<<NB, 256, 0, stream>>>(row_ptr, chunk_off, cursor, cnt, dinv);
  k_csr_fill<<<2048, 256, 0, stream>>>(ei, dinv, cursor, E);
  dim3 wtg(64, 3);
  k_wtrans<<<wtg, 256, 0, stream>>>(w1, w2, w3, wt1, wt2, wt3);

  // layer 1
  k_gemm<false><<<GB, 256, 0, stream>>>(x, wt1, T);
  k_agg<<<AB, 256, 0, stream>>>(T, row_ptr, E, dinv, b1, Hh);
  // layer 2
  k_gemm<true><<<GB, 256, 0, stream>>>(Hh, wt2, T);
  k_agg<<<AB, 256, 0, stream>>>(T, row_ptr, E, dinv, b2, Hh);
  // layer 3
  k_gemm<true><<<GB, 256, 0, stream>>>(Hh, wt3, T);
  k_agg<<<AB, 256, 0, stream>>>(T, row_ptr, E, dinv, b3, Hh);

  k_pool<<<PB, 128, 0, stream>>>(Hh, batch, pooled, gcnt);
  k_out<<<N_GRAPHS, 64, 0, stream>>>(pooled, gcnt, w_out, b_out, out);
}